// Round 1
// baseline (295.488 us; speedup 1.0000x reference)
//
#include <hip/hip_runtime.h>

#define N_ROWS 65536
#define DIM    512
#define BM     64
#define THREADS 512

typedef unsigned short ushort_t;
typedef __bf16 bf16x8 __attribute__((ext_vector_type(8)));
typedef float  f32x4  __attribute__((ext_vector_type(4)));

union BU { uint4 u; bf16x8 b; };

__device__ __forceinline__ unsigned f2bf(float f) {
    unsigned u = __float_as_uint(f);
    return (u + 0x7fffu + ((u >> 16) & 1u)) >> 16;   // RNE f32->bf16
}

// Transpose W (f32 [k][n]) -> WT (bf16 [n][k]); z=0 -> W1, z=1 -> W2.
__global__ void prep_weights(const float* __restrict__ W1,
                             const float* __restrict__ W2,
                             ushort_t* __restrict__ WT) {
    __shared__ float tile[32][33];
    const float* W = blockIdx.z ? W2 : W1;
    ushort_t* dst = WT + (size_t)blockIdx.z * DIM * DIM;
    int n0 = blockIdx.x * 32;
    int k0 = blockIdx.y * 32;
    for (int i = threadIdx.y; i < 32; i += 8)
        tile[i][threadIdx.x] = W[(size_t)(k0 + i) * DIM + n0 + threadIdx.x];
    __syncthreads();
    for (int i = threadIdx.y; i < 32; i += 8)
        dst[(size_t)(n0 + i) * DIM + k0 + threadIdx.x] =
            (ushort_t)f2bf(tile[threadIdx.x][i]);
}

// Fused: LN -> GEMM1(+bias,+GELU) -> GEMM2(+bias,+residual)
__global__ __launch_bounds__(THREADS, 2) void fused_resblock(
    const float* __restrict__ x, const float* __restrict__ gamma,
    const float* __restrict__ beta, const ushort_t* __restrict__ W1T,
    const float* __restrict__ b1, const ushort_t* __restrict__ W2T,
    const float* __restrict__ b2, float* __restrict__ out)
{
    __shared__ __align__(16) char smem[BM * DIM * 2];   // 64 KB, reused xn -> h1
    const int t    = threadIdx.x;
    const int wave = t >> 6;
    const int lane = t & 63;
    const int l15  = lane & 15;
    const int kb   = lane >> 4;          // 0..3
    const size_t rowbase = (size_t)blockIdx.x * BM;

    // ---------------- Phase 1: LayerNorm -> LDS (bf16, swizzled) -----------
    {
        const int r   = t >> 3;          // 0..63 (row in tile)
        const int sub = t & 7;           // 8 threads per row, 64 cols each
        const float4* xr = (const float4*)(x + (rowbase + r) * DIM) + sub * 16;
        float4 v[16];
        float s = 0.f, ss = 0.f;
        #pragma unroll
        for (int i = 0; i < 16; ++i) {
            v[i] = xr[i];
            s  += v[i].x + v[i].y + v[i].z + v[i].w;
            ss += v[i].x*v[i].x + v[i].y*v[i].y + v[i].z*v[i].z + v[i].w*v[i].w;
        }
        #pragma unroll
        for (int m = 1; m < 8; m <<= 1) {
            s  += __shfl_xor(s,  m);
            ss += __shfl_xor(ss, m);
        }
        const float mean = s * (1.f / 512.f);
        const float var  = ss * (1.f / 512.f) - mean * mean;
        const float rstd = rsqrtf(var + 1e-5f);
        const float4* g4 = (const float4*)gamma + sub * 16;
        const float4* e4 = (const float4*)beta  + sub * 16;
        const unsigned mask = (unsigned)((r & 7) << 4);
        const unsigned base = (unsigned)(r * 1024 + sub * 128);
        #pragma unroll
        for (int i = 0; i < 8; ++i) {
            float4 a = v[2*i], b = v[2*i+1];
            float4 ga = g4[2*i], gb = g4[2*i+1];
            float4 ea = e4[2*i], eb = e4[2*i+1];
            a.x = (a.x - mean) * rstd * ga.x + ea.x;
            a.y = (a.y - mean) * rstd * ga.y + ea.y;
            a.z = (a.z - mean) * rstd * ga.z + ea.z;
            a.w = (a.w - mean) * rstd * ga.w + ea.w;
            b.x = (b.x - mean) * rstd * gb.x + eb.x;
            b.y = (b.y - mean) * rstd * gb.y + eb.y;
            b.z = (b.z - mean) * rstd * gb.z + eb.z;
            b.w = (b.w - mean) * rstd * gb.w + eb.w;
            uint4 p;
            p.x = f2bf(a.x) | (f2bf(a.y) << 16);
            p.y = f2bf(a.z) | (f2bf(a.w) << 16);
            p.z = f2bf(b.x) | (f2bf(b.y) << 16);
            p.w = f2bf(b.z) | (f2bf(b.w) << 16);
            *(uint4*)(smem + ((base + (unsigned)(i * 16)) ^ mask)) = p;
        }
    }
    __syncthreads();

    // Common fragment addressing
    const unsigned amask = (unsigned)((l15 & 7) << 4);
    unsigned abase[4];
    #pragma unroll
    for (int m = 0; m < 4; ++m)
        abase[m] = (unsigned)((m * 16 + l15) * 1024 + kb * 16);

    f32x4 acc[4][4];

    // ---------------- Phase 2: GEMM1 + bias1 + exact GELU -> LDS -----------
    {
        #pragma unroll
        for (int m = 0; m < 4; ++m)
            #pragma unroll
            for (int n = 0; n < 4; ++n)
                acc[m][n] = f32x4{0.f, 0.f, 0.f, 0.f};

        const ushort_t* bp[4];
        #pragma unroll
        for (int n = 0; n < 4; ++n)
            bp[n] = W1T + (size_t)(wave * 64 + n * 16 + l15) * DIM + kb * 8;

        for (int k0 = 0; k0 < DIM; k0 += 32) {
            bf16x8 a[4], b[4];
            #pragma unroll
            for (int m = 0; m < 4; ++m) {
                BU u; u.u = *(const uint4*)(smem + ((abase[m] + (unsigned)(k0 * 2)) ^ amask));
                a[m] = u.b;
            }
            #pragma unroll
            for (int n = 0; n < 4; ++n) {
                BU u; u.u = *(const uint4*)(bp[n] + k0);
                b[n] = u.b;
            }
            #pragma unroll
            for (int m = 0; m < 4; ++m)
                #pragma unroll
                for (int n = 0; n < 4; ++n)
                    acc[m][n] = __builtin_amdgcn_mfma_f32_16x16x32_bf16(
                        a[m], b[n], acc[m][n], 0, 0, 0);
        }
        __syncthreads();   // all reads of xn done before overwriting with h1
        #pragma unroll
        for (int n = 0; n < 4; ++n) {
            const int c = wave * 64 + n * 16 + l15;
            const float bias = b1[c];
            #pragma unroll
            for (int m = 0; m < 4; ++m) {
                #pragma unroll
                for (int i = 0; i < 4; ++i) {
                    const int r = m * 16 + kb * 4 + i;
                    float vv = acc[m][n][i] + bias;
                    float gg = 0.5f * vv * (1.f + erff(vv * 0.70710678118f));
                    *(ushort_t*)(smem + (unsigned)((r * 1024 + c * 2) ^ ((r & 7) << 4)))
                        = (ushort_t)f2bf(gg);
                }
            }
        }
    }
    __syncthreads();

    // ---------------- Phase 3: GEMM2 + bias2 + residual -> out (f32) -------
    {
        #pragma unroll
        for (int m = 0; m < 4; ++m)
            #pragma unroll
            for (int n = 0; n < 4; ++n)
                acc[m][n] = f32x4{0.f, 0.f, 0.f, 0.f};

        const ushort_t* bp[4];
        #pragma unroll
        for (int n = 0; n < 4; ++n)
            bp[n] = W2T + (size_t)(wave * 64 + n * 16 + l15) * DIM + kb * 8;

        for (int k0 = 0; k0 < DIM; k0 += 32) {
            bf16x8 a[4], b[4];
            #pragma unroll
            for (int m = 0; m < 4; ++m) {
                BU u; u.u = *(const uint4*)(smem + ((abase[m] + (unsigned)(k0 * 2)) ^ amask));
                a[m] = u.b;
            }
            #pragma unroll
            for (int n = 0; n < 4; ++n) {
                BU u; u.u = *(const uint4*)(bp[n] + k0);
                b[n] = u.b;
            }
            #pragma unroll
            for (int m = 0; m < 4; ++m)
                #pragma unroll
                for (int n = 0; n < 4; ++n)
                    acc[m][n] = __builtin_amdgcn_mfma_f32_16x16x32_bf16(
                        a[m], b[n], acc[m][n], 0, 0, 0);
        }
        #pragma unroll
        for (int n = 0; n < 4; ++n) {
            const int c = wave * 64 + n * 16 + l15;
            const float bias = b2[c];
            #pragma unroll
            for (int m = 0; m < 4; ++m) {
                #pragma unroll
                for (int i = 0; i < 4; ++i) {
                    const int r = m * 16 + kb * 4 + i;
                    const size_t gi = (rowbase + (size_t)r) * DIM + (size_t)c;
                    out[gi] = x[gi] + (acc[m][n][i] + bias);
                }
            }
        }
    }
}

extern "C" void kernel_launch(void* const* d_in, const int* in_sizes, int n_in,
                              void* d_out, int out_size, void* d_ws, size_t ws_size,
                              hipStream_t stream) {
    const float* x     = (const float*)d_in[0];
    const float* gamma = (const float*)d_in[1];
    const float* beta  = (const float*)d_in[2];
    const float* W1    = (const float*)d_in[3];
    const float* b1    = (const float*)d_in[4];
    const float* W2    = (const float*)d_in[5];
    const float* b2    = (const float*)d_in[6];
    float* out = (float*)d_out;
    ushort_t* WT = (ushort_t*)d_ws;            // [0..512KB) W1T bf16, [512KB..1MB) W2T bf16

    prep_weights<<<dim3(DIM / 32, DIM / 32, 2), dim3(32, 8), 0, stream>>>(W1, W2, WT);
    fused_resblock<<<dim3(N_ROWS / BM), dim3(THREADS), 0, stream>>>(
        x, gamma, beta, WT, b1, WT + DIM * DIM, b2, out);
}